// Round 6
// baseline (483.928 us; speedup 1.0000x reference)
//
#include <hip/hip_runtime.h>

#define TSTEPS 48
#define OUT_STEPS 24
#define L2E 1.44269504088896340736f
#define ECLAMP 30.0f

typedef short bf16x8 __attribute__((ext_vector_type(8)));
typedef float f32x4 __attribute__((ext_vector_type(4)));
typedef unsigned int u32x4 __attribute__((ext_vector_type(4)));

// RNE bf16 hi + truncated-residual lo (weights; off hot path).
__device__ __forceinline__ void bf_split_rne(float f, short& hi, short& lo) {
    unsigned u = __builtin_bit_cast(unsigned, f);
    unsigned r = u + 0x7FFFu + ((u >> 16) & 1u);
    unsigned short hb = (unsigned short)(r >> 16);
    float hif = __builtin_bit_cast(float, (unsigned)hb << 16);
    float lof = f - hif;
    unsigned short lb = (unsigned short)(__builtin_bit_cast(unsigned, lof) >> 16);
    hi = (short)hb; lo = (short)lb;
}

// Truncation split packed into one dword: low16 = hi-bf16, high16 = lo-bf16.
__device__ __forceinline__ unsigned split_pack(float f) {
    unsigned u = __builtin_bit_cast(unsigned, f);
    float hif = __builtin_bit_cast(float, u & 0xFFFF0000u);
    float lof = f - hif;
    unsigned lo = __builtin_bit_cast(unsigned, lof);
    return (u >> 16) | (lo & 0xFFFF0000u);
}

// Per-tile exp2 pre-scale: gates i,f,o get -log2e; gate g (tiles 4,5) -2*log2e.
__device__ __forceinline__ float tile_scale(int t) {
    return (t == 4 || t == 5) ? (-2.0f * L2E) : (-L2E);
}

// Stage pre-scaled, permuted, hi/lo-split U^T fragments into LDS.
// Slot layout: fragLDS[(slot*64 + lane)*8] shorts; slot t = Ahi[t], slot 8+t = Alo[t].
// Row permutation: row R=16t+rho <-> gate=(t>>1), unit u=(rho>>2)*8+(t&1)*4+(rho&3).
__device__ __forceinline__ void stage_weights(const float* __restrict__ Uk,
                                              short* __restrict__ fragLDS,
                                              int lane, int LQ, int LC) {
    const int ulo = ((LC >> 2) << 3) + (LC & 3);
#pragma unroll
    for (int t = 0; t < 8; ++t) {
        const float s = tile_scale(t);
        const int col = (t >> 1) * 32 + ulo + (t & 1) * 4;
        bf16x8 ah, al;
#pragma unroll
        for (int j = 0; j < 8; ++j) {
            float wv = Uk[(LQ * 8 + j) * 128 + col] * s;
            short hb, lb; bf_split_rne(wv, hb, lb);
            ah[j] = hb; al[j] = lb;
        }
        *(bf16x8*)(fragLDS + (t * 64 + lane) * 8) = ah;
        *(bf16x8*)(fragLDS + ((8 + t) * 64 + lane) * 8) = al;
    }
}

// A4: per-tile C-init operand. A4[m=LC][k=j] = [Whi, Whi, Wlo, bhi, blo, 0,0,0]
// (pre-scaled). Nonzero only on LQ==0 lanes (k=0..7).
__device__ __forceinline__ void build_A4(const float* __restrict__ Wk,
                                         const float* __restrict__ bv,
                                         bf16x8* A4, int LQ, int LC) {
    const int ulo = ((LC >> 2) << 3) + (LC & 3);
#pragma unroll
    for (int t = 0; t < 8; ++t) {
        const float s = tile_scale(t);
        const int col = (t >> 1) * 32 + ulo + (t & 1) * 4;
        short whi, wlo, bhi, blo;
        bf_split_rne(Wk[col] * s, whi, wlo);
        bf_split_rne(bv[col] * s, bhi, blo);
        bf16x8 a = {whi, whi, wlo, bhi, blo, 0, 0, 0};
        u32x4 z4 = {0u, 0u, 0u, 0u};
        A4[t] = (LQ == 0) ? a : __builtin_bit_cast(bf16x8, z4);
    }
}

// One LSTM step. h enters/exits in MFMA B-frag layout (identity recurrence).
// xpack = (x_hi16)|(x_lo16<<16). c state is pre-scaled by -2*log2e.
__device__ __forceinline__ void lstm_step(unsigned xpack,
    const short* __restrict__ fragLDS, const bf16x8* A4,
    bf16x8& h_hi, bf16x8& h_lo, float* cs, float* hv, int lane, int LQ) {
    // B4 = [x_hi, x_lo, x_hi, 1, 1, 0,0,0] on LQ==0 lanes, else 0.
    unsigned w0 = xpack;
    unsigned w1 = (xpack & 0xFFFFu) | 0x3F800000u;  // [x_hi, bf16(1.0)]
    unsigned w2 = 0x00003F80u;                      // [bf16(1.0), 0]
    if (LQ != 0) { w0 = 0u; w1 = 0u; w2 = 0u; }
    u32x4 b4u = {w0, w1, w2, 0u};
    bf16x8 B4 = __builtin_bit_cast(bf16x8, b4u);

    bf16x8 nhh, nhl;
#pragma unroll
    for (int tl = 0; tl < 2; ++tl) {
        f32x4 z[4];
#pragma unroll
        for (int g = 0; g < 4; ++g) {
            const int t = 2 * g + tl;
            bf16x8 Ah = *(const bf16x8*)(fragLDS + (t * 64 + lane) * 8);
            bf16x8 Al = *(const bf16x8*)(fragLDS + ((8 + t) * 64 + lane) * 8);
            f32x4 a = {0.f, 0.f, 0.f, 0.f};
            a = __builtin_amdgcn_mfma_f32_16x16x32_bf16(A4[t], B4, a, 0, 0, 0);
            a = __builtin_amdgcn_mfma_f32_16x16x32_bf16(Al, h_hi, a, 0, 0, 0);
            a = __builtin_amdgcn_mfma_f32_16x16x32_bf16(Ah, h_lo, a, 0, 0, 0);
            a = __builtin_amdgcn_mfma_f32_16x16x32_bf16(Ah, h_hi, a, 0, 0, 0);
            z[g] = a;
        }
#pragma unroll
        for (int r = 0; r < 4; ++r) {
            const int j = tl * 4 + r;
            // z are pre-scaled: z_i' = -L2E*zi etc.; exp2 gives e^-z directly.
            float ei = __builtin_amdgcn_exp2f(__builtin_fminf(z[0][r], ECLAMP));
            float ef = __builtin_amdgcn_exp2f(__builtin_fminf(z[1][r], ECLAMP));
            float eg = __builtin_amdgcn_exp2f(__builtin_fminf(z[2][r], ECLAMP));
            float eo = __builtin_amdgcn_exp2f(__builtin_fminf(z[3][r], ECLAMP));
            float di = 1.0f + ei, df = 1.0f + ef, dg = 1.0f + eg, do_ = 1.0f + eo;
            float ngs = __builtin_fmaf(eg, 2.0f * L2E, -2.0f * L2E); // -2L2E*(1-eg)
            float t1 = di * dg;
            float t2 = cs[j] * t1;
            float num = __builtin_fmaf(ngs, df, t2);
            float cn = num * __builtin_amdgcn_rcpf(df * t1);  // scaled c'
            cs[j] = cn;
            float ec = __builtin_amdgcn_exp2f(__builtin_fminf(cn, ECLAMP)); // e^-2c
            float h = (1.0f - ec) * __builtin_amdgcn_rcpf(do_ * (1.0f + ec)); // o*tanh(c)
            hv[j] = h;
            unsigned u = __builtin_bit_cast(unsigned, h);
            float hif = __builtin_bit_cast(float, u & 0xFFFF0000u);
            float lof = h - hif;
            nhh[j] = (short)(u >> 16);
            nhl[j] = (short)(__builtin_bit_cast(unsigned, lof) >> 16);
        }
    }
    h_hi = nhh;
    h_lo = nhl;
}

__global__ __launch_bounds__(256, 4) void lstm_feedback_mfma5(
    const float* __restrict__ inputs,  // [B, 48]
    const float* __restrict__ Wk_w, const float* __restrict__ Uk_w, const float* __restrict__ b_w,
    const float* __restrict__ Wk_d, const float* __restrict__ Uk_d, const float* __restrict__ b_d,
    const float* __restrict__ Wd, const float* __restrict__ bd,
    float* __restrict__ out,           // [B, 24]
    int B) {
    const int tid = threadIdx.x;       // 4 waves per block
    const int w = tid >> 6;
    const int lane = tid & 63;
    const int LQ = lane >> 4;
    const int LC = lane & 15;          // lane's batch column within its wave
    const int mblk = blockIdx.x * 64;

    __shared__ __align__(16) short fragLDS[16 * 64 * 8];  // 16 KB, shared by all 4 waves
    __shared__ unsigned xsplit[4][16 * 49];               // packed hi|lo x, stride 49
    __shared__ float predbuf[4][16 * 25];

    // Cooperative load + pre-split of the block's 64x48 inputs.
    for (int i = tid; i < 64 * TSTEPS; i += 256) {
        int m = i / TSTEPS, t = i - m * TSTEPS;
        xsplit[m >> 4][(m & 15) * 49 + t] = split_pack(inputs[(long)mblk * TSTEPS + i]);
    }
    if (w == 0) stage_weights(Uk_w, fragLDS, lane, LQ, LC);

    bf16x8 A4[8];
    build_A4(Wk_w, b_w, A4, LQ, LC);

    bf16x8 h_hi = {0, 0, 0, 0, 0, 0, 0, 0};
    bf16x8 h_lo = {0, 0, 0, 0, 0, 0, 0, 0};
    float cs[8] = {0, 0, 0, 0, 0, 0, 0, 0};  // scaled cell state (-2*log2e * c)
    float hv[8];

    float wdv[8];
#pragma unroll
    for (int j = 0; j < 8; ++j) wdv[j] = Wd[LQ * 8 + j];
    const float bdv = bd[0];

    __syncthreads();  // fragLDS + xsplit visible

    const unsigned* __restrict__ xcol = &xsplit[w][LC * 49];

    // ---- warmup: 48 steps ----
    for (int t = 0; t < TSTEPS; ++t) {
        asm volatile("" ::: "memory");  // block LICM of per-step LDS frag reads
        lstm_step(xcol[t], fragLDS, A4, h_hi, h_lo, cs, hv, lane, LQ);
    }

    // ---- first prediction ----
    float p = 0.0f;
#pragma unroll
    for (int j = 0; j < 8; ++j) p = __builtin_fmaf(hv[j], wdv[j], p);
    p += __shfl_xor(p, 16);
    p += __shfl_xor(p, 32);
    p += bdv;
    if (LQ == 0) predbuf[w][LC * 25 + 0] = p;

    // ---- swap in decode weights (wave 0 restages; all rebuild A4) ----
    __syncthreads();  // all done reading warmup frags
    if (w == 0) stage_weights(Uk_d, fragLDS, lane, LQ, LC);
    build_A4(Wk_d, b_d, A4, LQ, LC);
    __syncthreads();  // decode frags visible

    for (int s = 1; s < OUT_STEPS; ++s) {
        asm volatile("" ::: "memory");
        lstm_step(split_pack(p), fragLDS, A4, h_hi, h_lo, cs, hv, lane, LQ);
        p = 0.0f;
#pragma unroll
        for (int j = 0; j < 8; ++j) p = __builtin_fmaf(hv[j], wdv[j], p);
        p += __shfl_xor(p, 16);
        p += __shfl_xor(p, 32);
        p += bdv;
        if (LQ == 0) predbuf[w][LC * 25 + s] = p;
    }

    // ---- coalesced output flush ----
    __syncthreads();
    for (int i = tid; i < 64 * OUT_STEPS; i += 256) {
        int m = i / OUT_STEPS, s = i - m * OUT_STEPS;
        out[(long)mblk * OUT_STEPS + i] = predbuf[m >> 4][(m & 15) * 25 + s];
    }
}

extern "C" void kernel_launch(void* const* d_in, const int* in_sizes, int n_in,
                              void* d_out, int out_size, void* d_ws, size_t ws_size,
                              hipStream_t stream) {
    const float* inputs = (const float*)d_in[0];
    const float* Wk_w   = (const float*)d_in[1];
    const float* Uk_w   = (const float*)d_in[2];
    const float* b_w    = (const float*)d_in[3];
    const float* Wk_d   = (const float*)d_in[4];
    const float* Uk_d   = (const float*)d_in[5];
    const float* b_d    = (const float*)d_in[6];
    const float* Wd     = (const float*)d_in[7];
    const float* bd     = (const float*)d_in[8];
    float* out = (float*)d_out;

    const int B = in_sizes[0] / TSTEPS;
    const int grid = (B + 63) / 64;   // 64 batch rows per 256-thread block
    lstm_feedback_mfma5<<<grid, 256, 0, stream>>>(
        inputs, Wk_w, Uk_w, b_w, Wk_d, Uk_d, b_d, Wd, bd, out, B);
}

// Round 7
// 433.290 us; speedup vs baseline: 1.1169x; 1.1169x over previous
//
#include <hip/hip_runtime.h>

#define TSTEPS 48
#define OUT_STEPS 24
#define L2E 1.44269504088896340736f
#define ECLAMP 30.0f

typedef short bf16x8 __attribute__((ext_vector_type(8)));
typedef float f32x4 __attribute__((ext_vector_type(4)));

// RNE bf16 hi + truncated-residual lo (weights; off hot path).
__device__ __forceinline__ void bf_split_rne(float f, short& hi, short& lo) {
    unsigned u = __builtin_bit_cast(unsigned, f);
    unsigned r = u + 0x7FFFu + ((u >> 16) & 1u);
    unsigned short hb = (unsigned short)(r >> 16);
    float hif = __builtin_bit_cast(float, (unsigned)hb << 16);
    float lof = f - hif;
    unsigned short lb = (unsigned short)(__builtin_bit_cast(unsigned, lof) >> 16);
    hi = (short)hb; lo = (short)lb;
}

// Per-tile exp2 pre-scale: gates i,f,o get -log2e; gate g (tiles 4,5) -2*log2e.
__device__ __forceinline__ float tile_scale(int t) {
    return (t == 4 || t == 5) ? (-2.0f * L2E) : (-L2E);
}

// A-fragments of PRE-SCALED permuted U^T (hi/lo split) + per-lane pre-scaled
// Wk/b constants in D order — all register-resident.
// Row permutation: row R=16t+rho <-> gate=(t>>1), unit u=(rho>>2)*8+(t&1)*4+(rho&3).
__device__ __forceinline__ void load_weights(const float* __restrict__ Uk,
                                             const float* __restrict__ Wk,
                                             const float* __restrict__ bv,
                                             bf16x8* Ahi, bf16x8* Alo,
                                             f32x4* wkfr, f32x4* bfr, int LQ, int LC) {
    const int ulo = ((LC >> 2) << 3) + (LC & 3);
#pragma unroll
    for (int t = 0; t < 8; ++t) {
        const float s = tile_scale(t);
        const int col = (t >> 1) * 32 + ulo + (t & 1) * 4;
        bf16x8 ah, al;
#pragma unroll
        for (int j = 0; j < 8; ++j) {
            float w = Uk[(LQ * 8 + j) * 128 + col] * s;
            short hb, lb; bf_split_rne(w, hb, lb);
            ah[j] = hb; al[j] = lb;
        }
        Ahi[t] = ah; Alo[t] = al;
        const int colb = (t >> 1) * 32 + LQ * 8 + (t & 1) * 4;
#pragma unroll
        for (int r = 0; r < 4; ++r) {
            wkfr[t][r] = Wk[colb + r] * s;
            bfr[t][r]  = bv[colb + r] * s;
        }
    }
}

// One LSTM step; h enters/exits in MFMA B-frag layout (identity recurrence).
// All z pre-scaled for exp2 (z' = -L2E*z; g-gate & c-state by -2*L2E).
// 7 trans/unit: 5 exp2 + 2 rcp. Only zg' and cs need clamps (bound analysis;
// R5 passed with exactly these two).
__device__ __forceinline__ void lstm_step(float x,
    const bf16x8* Ahi, const bf16x8* Alo,
    const f32x4* wkfr, const f32x4* bfr,
    bf16x8& h_hi, bf16x8& h_lo, float* cs, float* hv) {
    f32x4 acc[8];
#pragma unroll
    for (int t = 0; t < 8; ++t) {
        f32x4 a;
#pragma unroll
        for (int r = 0; r < 4; ++r) a[r] = __builtin_fmaf(x, wkfr[t][r], bfr[t][r]);
        a = __builtin_amdgcn_mfma_f32_16x16x32_bf16(Alo[t], h_hi, a, 0, 0, 0);
        a = __builtin_amdgcn_mfma_f32_16x16x32_bf16(Ahi[t], h_lo, a, 0, 0, 0);
        a = __builtin_amdgcn_mfma_f32_16x16x32_bf16(Ahi[t], h_hi, a, 0, 0, 0);
        acc[t] = a;
    }
    bf16x8 nhh, nhl;
#pragma unroll
    for (int tl = 0; tl < 2; ++tl) {
#pragma unroll
        for (int rp = 0; rp < 2; ++rp) {
#pragma unroll
            for (int rr = 0; rr < 2; ++rr) {
                const int r = 2 * rp + rr;
                const int j = tl * 4 + r;
                float ei = __builtin_amdgcn_exp2f(acc[0 + tl][r]);                        // e^-zi
                float ef = __builtin_amdgcn_exp2f(acc[2 + tl][r]);                        // e^-zf
                float eg = __builtin_amdgcn_exp2f(__builtin_fminf(acc[4 + tl][r], ECLAMP)); // e^-2zg
                float eo = __builtin_amdgcn_exp2f(acc[6 + tl][r]);                        // e^-zo
                float di = 1.0f + ei, df = 1.0f + ef, dg = 1.0f + eg, do_ = 1.0f + eo;
                float ngs = __builtin_fmaf(eg, 2.0f * L2E, -2.0f * L2E);  // -2L2E*(1-eg)
                float t1 = di * dg;
                float t2 = cs[j] * t1;
                float num = __builtin_fmaf(ngs, df, t2);
                float cn = num * __builtin_amdgcn_rcpf(df * t1);          // scaled c'
                cs[j] = cn;
                float ec = __builtin_amdgcn_exp2f(__builtin_fminf(cn, ECLAMP));  // e^-2c
                float h = (1.0f - ec) * __builtin_amdgcn_rcpf(do_ * (1.0f + ec)); // o*tanh(c)
                hv[j] = h;
                unsigned u = __builtin_bit_cast(unsigned, h);
                float hif = __builtin_bit_cast(float, u & 0xFFFF0000u);
                float lof = h - hif;
                nhh[j] = (short)(u >> 16);
                nhl[j] = (short)(__builtin_bit_cast(unsigned, lof) >> 16);
            }
        }
    }
    h_hi = nhh;
    h_lo = nhl;
}

// (256,2): VGPR cap 256; natural allocation ~130 arch + ~64 acc -> 2 waves/SIMD.
// We are issue-bound (R5: VALU 73.5 + MFMA 23.6 = 97%), so occupancy beyond
// this is worthless — R6 proved raising it while adding instructions regresses.
__global__ __launch_bounds__(256, 2) void lstm_feedback_mfma6(
    const float* __restrict__ inputs,  // [B, 48]
    const float* __restrict__ Wk_w, const float* __restrict__ Uk_w, const float* __restrict__ b_w,
    const float* __restrict__ Wk_d, const float* __restrict__ Uk_d, const float* __restrict__ b_d,
    const float* __restrict__ Wd, const float* __restrict__ bd,
    float* __restrict__ out,           // [B, 24]
    int B) {
    const int tid = threadIdx.x;       // 4 independent waves per block
    const int w = tid >> 6;
    const int lane = tid & 63;
    const int LQ = lane >> 4;
    const int LC = lane & 15;          // lane's batch column within its wave
    const int mblk = blockIdx.x * 64;

    __shared__ float xbuf[4][16 * 49];    // stride 49: conflict-free column reads
    __shared__ float predbuf[4][16 * 25]; // stride 25: conflict-free scattered writes

    // Block cooperatively loads its 64x48 input tile (coalesced).
    for (int i = tid; i < 64 * TSTEPS; i += 256) {
        int m = i / TSTEPS, t = i - m * TSTEPS;
        xbuf[m >> 4][(m & 15) * 49 + t] = inputs[(long)mblk * TSTEPS + i];
    }

    bf16x8 Ahi[8], Alo[8];
    f32x4 wkfr[8], bfr[8];
    load_weights(Uk_w, Wk_w, b_w, Ahi, Alo, wkfr, bfr, LQ, LC);

    bf16x8 h_hi = {0, 0, 0, 0, 0, 0, 0, 0};
    bf16x8 h_lo = {0, 0, 0, 0, 0, 0, 0, 0};
    float cs[8] = {0, 0, 0, 0, 0, 0, 0, 0};  // scaled cell state (-2*log2e * c)
    float hv[8];

    float wdv[8];
#pragma unroll
    for (int j = 0; j < 8; ++j) wdv[j] = Wd[LQ * 8 + j];
    const float bdv = bd[0];

    __syncthreads();  // xbuf visible

    const float* __restrict__ xcol = &xbuf[w][LC * 49];

    // ---- warmup: 48 steps, no LDS/barriers inside ----
    for (int t = 0; t < TSTEPS; ++t) {
        lstm_step(xcol[t], Ahi, Alo, wkfr, bfr, h_hi, h_lo, cs, hv);
    }

    // ---- first prediction: partial dot + 2-shuffle butterfly ----
    float p = 0.0f;
#pragma unroll
    for (int j = 0; j < 8; ++j) p = __builtin_fmaf(hv[j], wdv[j], p);
    p += __shfl_xor(p, 16);
    p += __shfl_xor(p, 32);
    p += bdv;                          // all lanes of column LC hold pred(batch LC)
    if (LQ == 0) predbuf[w][LC * 25 + 0] = p;

    // ---- decode weights ----
    load_weights(Uk_d, Wk_d, b_d, Ahi, Alo, wkfr, bfr, LQ, LC);

    for (int s = 1; s < OUT_STEPS; ++s) {
        lstm_step(p, Ahi, Alo, wkfr, bfr, h_hi, h_lo, cs, hv);
        p = 0.0f;
#pragma unroll
        for (int j = 0; j < 8; ++j) p = __builtin_fmaf(hv[j], wdv[j], p);
        p += __shfl_xor(p, 16);
        p += __shfl_xor(p, 32);
        p += bdv;
        if (LQ == 0) predbuf[w][LC * 25 + s] = p;
    }

    // ---- coalesced output flush ----
    __syncthreads();
    for (int i = tid; i < 64 * OUT_STEPS; i += 256) {
        int m = i / OUT_STEPS, s = i - m * OUT_STEPS;
        out[(long)mblk * OUT_STEPS + i] = predbuf[m >> 4][(m & 15) * 25 + s];
    }
}

extern "C" void kernel_launch(void* const* d_in, const int* in_sizes, int n_in,
                              void* d_out, int out_size, void* d_ws, size_t ws_size,
                              hipStream_t stream) {
    const float* inputs = (const float*)d_in[0];
    const float* Wk_w   = (const float*)d_in[1];
    const float* Uk_w   = (const float*)d_in[2];
    const float* b_w    = (const float*)d_in[3];
    const float* Wk_d   = (const float*)d_in[4];
    const float* Uk_d   = (const float*)d_in[5];
    const float* b_d    = (const float*)d_in[6];
    const float* Wd     = (const float*)d_in[7];
    const float* bd     = (const float*)d_in[8];
    float* out = (float*)d_out;

    const int B = in_sizes[0] / TSTEPS;
    const int grid = (B + 63) / 64;   // 64 batch rows per 256-thread block
    lstm_feedback_mfma6<<<grid, 256, 0, stream>>>(
        inputs, Wk_w, Uk_w, b_w, Wk_d, Uk_d, b_d, Wd, bd, out, B);
}

// Round 8
// 429.112 us; speedup vs baseline: 1.1277x; 1.0097x over previous
//
#include <hip/hip_runtime.h>

#define TSTEPS 48
#define OUT_STEPS 24
#define L2E 1.44269504088896340736f
#define ECLAMP 30.0f

typedef short bf16x8 __attribute__((ext_vector_type(8)));
typedef float f32x4 __attribute__((ext_vector_type(4)));

// RNE bf16 hi + truncated-residual lo (weights; off hot path).
__device__ __forceinline__ void bf_split_rne(float f, short& hi, short& lo) {
    unsigned u = __builtin_bit_cast(unsigned, f);
    unsigned r = u + 0x7FFFu + ((u >> 16) & 1u);
    unsigned short hb = (unsigned short)(r >> 16);
    float hif = __builtin_bit_cast(float, (unsigned)hb << 16);
    float lof = f - hif;
    unsigned short lb = (unsigned short)(__builtin_bit_cast(unsigned, lof) >> 16);
    hi = (short)hb; lo = (short)lb;
}

// Per-tile exp2 pre-scale: gates i,f,o get -log2e; gate g (tiles 4,5) -2*log2e.
__device__ __forceinline__ float tile_scale(int t) {
    return (t == 4 || t == 5) ? (-2.0f * L2E) : (-L2E);
}

// A-fragments of PRE-SCALED permuted U^T (hi/lo split), register-resident.
// Row permutation: row R=16t+rho <-> gate=(t>>1), unit u=(rho>>2)*8+(t&1)*4+(rho&3).
__device__ __forceinline__ void load_Ufrags(const float* __restrict__ Uk,
                                            bf16x8* Ahi, bf16x8* Alo, int LQ, int LC) {
    const int ulo = ((LC >> 2) << 3) + (LC & 3);
#pragma unroll
    for (int t = 0; t < 8; ++t) {
        const float s = tile_scale(t);
        const int col = (t >> 1) * 32 + ulo + (t & 1) * 4;
        bf16x8 ah, al;
#pragma unroll
        for (int j = 0; j < 8; ++j) {
            float w = Uk[(LQ * 8 + j) * 128 + col] * s;
            short hb, lb; bf_split_rne(w, hb, lb);
            ah[j] = hb; al[j] = lb;
        }
        Ahi[t] = ah; Alo[t] = al;
    }
}

// One LSTM step; h enters/exits in MFMA B-frag layout (identity recurrence).
// Wk/b per-lane constants come from LDS (quad-uniform broadcast, conflict-free).
// Two gate-halves: only 4 accumulators live at once.
// If NEED_P: fold h . Wd into pp (pred partial) inside the loop.
template <bool NEED_P>
__device__ __forceinline__ float lstm_step(float x,
    const bf16x8* Ahi, const bf16x8* Alo,
    const float* __restrict__ wkb_cell,   // &wkb[cell][0][0][0]; idx (t*4+LQ)*8
    bf16x8& h_hi, bf16x8& h_lo, float* cs,
    const float* wdv, int LQ) {
    float pp = 0.0f;
    bf16x8 nhh, nhl;
#pragma unroll
    for (int tl = 0; tl < 2; ++tl) {
        f32x4 acc[4];
#pragma unroll
        for (int g = 0; g < 4; ++g) {
            const int t = 2 * g + tl;
            const float* wb = wkb_cell + (t * 4 + LQ) * 8;
            f32x4 wk = *(const f32x4*)wb;         // ds_read_b128 (broadcast)
            f32x4 bb = *(const f32x4*)(wb + 4);   // ds_read_b128
            f32x4 a;
#pragma unroll
            for (int r = 0; r < 4; ++r) a[r] = __builtin_fmaf(x, wk[r], bb[r]);
            a = __builtin_amdgcn_mfma_f32_16x16x32_bf16(Alo[t], h_hi, a, 0, 0, 0);
            a = __builtin_amdgcn_mfma_f32_16x16x32_bf16(Ahi[t], h_lo, a, 0, 0, 0);
            a = __builtin_amdgcn_mfma_f32_16x16x32_bf16(Ahi[t], h_hi, a, 0, 0, 0);
            acc[g] = a;
        }
#pragma unroll
        for (int r = 0; r < 4; ++r) {
            const int j = tl * 4 + r;
            // z pre-scaled: exp2 gives e^-z (e^-2z for g) directly.
            float ei = __builtin_amdgcn_exp2f(acc[0][r]);
            float ef = __builtin_amdgcn_exp2f(acc[1][r]);
            float eg = __builtin_amdgcn_exp2f(__builtin_fminf(acc[2][r], ECLAMP));
            float eo = __builtin_amdgcn_exp2f(acc[3][r]);
            float di = 1.0f + ei, df = 1.0f + ef, dg = 1.0f + eg, do_ = 1.0f + eo;
            float ngs = __builtin_fmaf(eg, 2.0f * L2E, -2.0f * L2E);  // -2L2E*(1-eg)
            float t1 = di * dg;
            float t2 = cs[j] * t1;
            float num = __builtin_fmaf(ngs, df, t2);
            float cn = num * __builtin_amdgcn_rcpf(df * t1);          // scaled c'
            cs[j] = cn;
            float ec = __builtin_amdgcn_exp2f(__builtin_fminf(cn, ECLAMP)); // e^-2c
            float h = (1.0f - ec) * __builtin_amdgcn_rcpf(do_ * (1.0f + ec)); // o*tanh(c)
            if constexpr (NEED_P) pp = __builtin_fmaf(h, wdv[j], pp);
            unsigned u = __builtin_bit_cast(unsigned, h);
            float hif = __builtin_bit_cast(float, u & 0xFFFF0000u);
            float lof = h - hif;
            nhh[j] = (short)(u >> 16);
            nhl[j] = (short)(__builtin_bit_cast(unsigned, lof) >> 16);
        }
    }
    h_hi = nhh;
    h_lo = nhl;
    return pp;
}

// (256,3): VGPR cap ~170. Demand after the register diet ~110-130 -> 3 waves/SIMD.
// R5/R7 showed 26% VALU idle at 2 waves; 3 waves saturates issue.
__global__ __launch_bounds__(256, 3) void lstm_feedback_mfma7(
    const float* __restrict__ inputs,  // [B, 48]
    const float* __restrict__ Wk_w, const float* __restrict__ Uk_w, const float* __restrict__ b_w,
    const float* __restrict__ Wk_d, const float* __restrict__ Uk_d, const float* __restrict__ b_d,
    const float* __restrict__ Wd, const float* __restrict__ bd,
    float* __restrict__ out,           // [B, 24]
    int B) {
    const int tid = threadIdx.x;       // 4 independent waves per block
    const int w = tid >> 6;
    const int lane = tid & 63;
    const int LQ = lane >> 4;
    const int LC = lane & 15;          // lane's batch column within its wave
    const int mblk = blockIdx.x * 64;

    __shared__ float xbuf[4][16 * 49];     // stride 49: conflict-free column reads
    __shared__ float predbuf[4][16 * 25];  // stride 25: conflict-free scattered writes
    __shared__ __align__(16) float wkb[2][8][4][8];  // [cell][tile][LQ][wk0..3,b0..3]

    // Stage BOTH cells' pre-scaled Wk/b (quad-uniform data; 1 value pair per thread).
    {
        const int cell = tid >> 7, t = (tid >> 4) & 7, q = (tid >> 2) & 3, r = tid & 3;
        const float* Wks = cell ? Wk_d : Wk_w;
        const float* bvs = cell ? b_d : b_w;
        const float s = tile_scale(t);
        const int colb = (t >> 1) * 32 + q * 8 + (t & 1) * 4 + r;
        wkb[cell][t][q][r]     = Wks[colb] * s;
        wkb[cell][t][q][4 + r] = bvs[colb] * s;
    }

    // Block cooperatively loads its 64x48 input tile (coalesced).
    for (int i = tid; i < 64 * TSTEPS; i += 256) {
        int m = i / TSTEPS, t = i - m * TSTEPS;
        xbuf[m >> 4][(m & 15) * 49 + t] = inputs[(long)mblk * TSTEPS + i];
    }

    bf16x8 Ahi[8], Alo[8];
    load_Ufrags(Uk_w, Ahi, Alo, LQ, LC);

    bf16x8 h_hi = {0, 0, 0, 0, 0, 0, 0, 0};
    bf16x8 h_lo = {0, 0, 0, 0, 0, 0, 0, 0};
    float cs[8] = {0, 0, 0, 0, 0, 0, 0, 0};  // scaled cell state (-2*log2e * c)

    __syncthreads();  // xbuf + wkb visible

    const float* __restrict__ xcol = &xbuf[w][LC * 49];
    const float* __restrict__ wkb_w = &wkb[0][0][0][0];
    const float* __restrict__ wkb_d = &wkb[1][0][0][0];

    // ---- warmup: steps 0..46 (pred not needed) ----
    for (int t = 0; t < TSTEPS - 1; ++t) {
        asm volatile("" ::: "memory");  // keep wkb ds_reads inside the loop
        lstm_step<false>(xcol[t], Ahi, Alo, wkb_w, h_hi, h_lo, cs, nullptr, LQ);
    }

    // Wd/bd loaded only now (keeps warmup register pressure down).
    float wdv[8];
#pragma unroll
    for (int j = 0; j < 8; ++j) wdv[j] = Wd[LQ * 8 + j];
    const float bdv = bd[0];

    // ---- last warmup step, with pred fold ----
    asm volatile("" ::: "memory");
    float p = lstm_step<true>(xcol[TSTEPS - 1], Ahi, Alo, wkb_w, h_hi, h_lo, cs, wdv, LQ);
    p += __shfl_xor(p, 16);
    p += __shfl_xor(p, 32);
    p += bdv;                          // all lanes of column LC hold pred(batch LC)
    if (LQ == 0) predbuf[w][LC * 25 + 0] = p;

    // ---- decode: swap U fragments; wkb for decode already staged ----
    load_Ufrags(Uk_d, Ahi, Alo, LQ, LC);

    for (int s = 1; s < OUT_STEPS; ++s) {
        asm volatile("" ::: "memory");
        p = lstm_step<true>(p, Ahi, Alo, wkb_d, h_hi, h_lo, cs, wdv, LQ);
        p += __shfl_xor(p, 16);
        p += __shfl_xor(p, 32);
        p += bdv;
        if (LQ == 0) predbuf[w][LC * 25 + s] = p;
    }

    // ---- coalesced output flush ----
    __syncthreads();
    for (int i = tid; i < 64 * OUT_STEPS; i += 256) {
        int m = i / OUT_STEPS, s = i - m * OUT_STEPS;
        out[(long)mblk * OUT_STEPS + i] = predbuf[m >> 4][(m & 15) * 25 + s];
    }
}

extern "C" void kernel_launch(void* const* d_in, const int* in_sizes, int n_in,
                              void* d_out, int out_size, void* d_ws, size_t ws_size,
                              hipStream_t stream) {
    const float* inputs = (const float*)d_in[0];
    const float* Wk_w   = (const float*)d_in[1];
    const float* Uk_w   = (const float*)d_in[2];
    const float* b_w    = (const float*)d_in[3];
    const float* Wk_d   = (const float*)d_in[4];
    const float* Uk_d   = (const float*)d_in[5];
    const float* b_d    = (const float*)d_in[6];
    const float* Wd     = (const float*)d_in[7];
    const float* bd     = (const float*)d_in[8];
    float* out = (float*)d_out;

    const int B = in_sizes[0] / TSTEPS;
    const int grid = (B + 63) / 64;   // 64 batch rows per 256-thread block
    lstm_feedback_mfma7<<<grid, 256, 0, stream>>>(
        inputs, Wk_w, Uk_w, b_w, Wk_d, Uk_d, b_d, Wd, bd, out, B);
}